// Round 6
// baseline (128.408 us; speedup 1.0000x reference)
//
#include <hip/hip_runtime.h>

#define LN_EPS 1e-5f

__device__ __forceinline__ float wred_max(float v) {
#pragma unroll
    for (int off = 32; off; off >>= 1) v = fmaxf(v, __shfl_xor(v, off, 64));
    return v;
}
__device__ __forceinline__ float wred_sum(float v) {
#pragma unroll
    for (int off = 32; off; off >>= 1) v += __shfl_xor(v, off, 64);
    return v;
}

// Kernel 1: hi_ws[row][e] = x[row]·W1[:256][e] + b1[e]
//           hjT[b][e][m]  = x[b*256+m]·W1[256:][e]   (transposed store)
// 256 blocks × 256 thr, 8 rows/block. Wave w: half = w>>1, rows (w&1)*4..+3.
// Lane owns 4 cols e=4*lane..+3. W1 traffic: 1 MB/block (vs 1 MB/4rows before).
__global__ __launch_bounds__(256) void k_gemm_hij(
    const float* __restrict__ x,    // [2048,256]
    const float* __restrict__ W1,   // [512,256]
    const float* __restrict__ b1,   // [256]
    float* __restrict__ hi_ws,      // [2048,256]
    float* __restrict__ hjT)        // [8,256,256] (b, e, m)
{
    __shared__ __align__(16) float xs[8][256];
    const int t = threadIdx.x;
    const int lane = t & 63, w = t >> 6;
    const int row0 = blockIdx.x * 8;

    ((float4*)xs)[t]       = ((const float4*)(x + (size_t)row0 * 256))[t];
    ((float4*)xs)[t + 256] = ((const float4*)(x + (size_t)row0 * 256))[t + 256];
    __syncthreads();

    const int half = w >> 1;
    const int r0 = (w & 1) * 4;
    const float* Wb = W1 + (size_t)half * 65536 + 4 * lane;

    float acc[4][4];   // [row][col]
#pragma unroll
    for (int r = 0; r < 4; r++)
#pragma unroll
        for (int c = 0; c < 4; c++) acc[r][c] = 0.f;

#pragma unroll 2
    for (int k = 0; k < 256; k += 4) {
        float4 q0 = *(const float4*)(Wb + (size_t)(k + 0) * 256);
        float4 q1 = *(const float4*)(Wb + (size_t)(k + 1) * 256);
        float4 q2 = *(const float4*)(Wb + (size_t)(k + 2) * 256);
        float4 q3 = *(const float4*)(Wb + (size_t)(k + 3) * 256);
#pragma unroll
        for (int r = 0; r < 4; r++) {
            float4 xr = *(const float4*)&xs[r0 + r][k];
            acc[r][0] = fmaf(xr.x, q0.x, acc[r][0]);
            acc[r][0] = fmaf(xr.y, q1.x, acc[r][0]);
            acc[r][0] = fmaf(xr.z, q2.x, acc[r][0]);
            acc[r][0] = fmaf(xr.w, q3.x, acc[r][0]);
            acc[r][1] = fmaf(xr.x, q0.y, acc[r][1]);
            acc[r][1] = fmaf(xr.y, q1.y, acc[r][1]);
            acc[r][1] = fmaf(xr.z, q2.y, acc[r][1]);
            acc[r][1] = fmaf(xr.w, q3.y, acc[r][1]);
            acc[r][2] = fmaf(xr.x, q0.z, acc[r][2]);
            acc[r][2] = fmaf(xr.y, q1.z, acc[r][2]);
            acc[r][2] = fmaf(xr.z, q2.z, acc[r][2]);
            acc[r][2] = fmaf(xr.w, q3.z, acc[r][2]);
            acc[r][3] = fmaf(xr.x, q0.w, acc[r][3]);
            acc[r][3] = fmaf(xr.y, q1.w, acc[r][3]);
            acc[r][3] = fmaf(xr.z, q2.w, acc[r][3]);
            acc[r][3] = fmaf(xr.w, q3.w, acc[r][3]);
        }
    }

    if (half == 0) {
        float4 b4 = *(const float4*)(b1 + 4 * lane);
#pragma unroll
        for (int r = 0; r < 4; r++) {
            float4 o = make_float4(acc[r][0] + b4.x, acc[r][1] + b4.y,
                                   acc[r][2] + b4.z, acc[r][3] + b4.w);
            *(float4*)&hi_ws[(size_t)(row0 + r0 + r) * 256 + 4 * lane] = o;
        }
    } else {
        const int b = row0 >> 8;
        const int m0 = (row0 & 255) + r0;
#pragma unroll
        for (int e = 0; e < 4; e++) {
            float4 v = make_float4(acc[0][e], acc[1][e], acc[2][e], acc[3][e]);
            *(float4*)&hjT[(size_t)b * 65536 + (size_t)(4 * lane + e) * 256 + m0] = v;
        }
    }
}

// Kernel 2: 4 n's per block, 512 blocks × 4 waves.
// XCD swizzle: b = blockIdx & 7 -> all blocks of batch b on XCD b (blockIdx%8
// round-robin). Per-XCD L2 working set ~1 MB (hjT[b]+x[b]+hi[b]+Wp) << 4 MB.
__global__ __launch_bounds__(256) void k_fused(
    const float* __restrict__ x,      // [8,256,256]
    const float* __restrict__ hi_ws,  // [2048,256] (b1 folded)
    const float* __restrict__ hjT,    // [8,256,256] (b, d, m)
    const float* __restrict__ W2, const float* __restrict__ b2,
    const float* __restrict__ Wp, const float* __restrict__ bp,
    const float* __restrict__ gma, const float* __restrict__ bta,
    float* __restrict__ out)
{
    const int t = threadIdx.x;
    const int lane = t & 63, w = t >> 6;
    const int b = blockIdx.x & 7;          // XCD-local batch
    const int n0 = (blockIdx.x >> 3) * 4;  // n-tile within batch
    const int bn0 = b * 256 + n0;

    __shared__ __align__(16) float hi_s[4][256];
    __shared__ __align__(16) float w2_s[256];
    __shared__ __align__(16) float wt_s[4][256];
    __shared__ __align__(16) float ctx_s[4][256];
    __shared__ __align__(16) float sred[4][4][256];   // [wave][n][out]
    __shared__ float part[8][4];

#pragma unroll
    for (int i = 0; i < 4; i++) hi_s[i][t] = hi_ws[(size_t)(bn0 + i) * 256 + t];
    w2_s[t] = W2[t];
    __syncthreads();

    // ---- phase 1: partial scores. wave w: d in [64w,64w+64); lane: m=4*lane..+3
    {
        const float* hjp = hjT + (size_t)b * 65536 + (size_t)(w * 64) * 256 + 4 * lane;
        float sp[4][4];
#pragma unroll
        for (int n = 0; n < 4; n++)
#pragma unroll
            for (int j = 0; j < 4; j++) sp[n][j] = 0.f;

#pragma unroll 4
        for (int dc = 0; dc < 64; dc += 4) {
            float4 h0 = *(const float4*)(hjp + (size_t)(dc + 0) * 256);
            float4 h1 = *(const float4*)(hjp + (size_t)(dc + 1) * 256);
            float4 h2 = *(const float4*)(hjp + (size_t)(dc + 2) * 256);
            float4 h3 = *(const float4*)(hjp + (size_t)(dc + 3) * 256);
            float4 wq = *(const float4*)&w2_s[w * 64 + dc];
#pragma unroll
            for (int n = 0; n < 4; n++) {
                float4 hi4 = *(const float4*)&hi_s[n][w * 64 + dc];
                sp[n][0] = fmaf(fmaxf(hi4.x + h0.x, 0.f), wq.x, sp[n][0]);
                sp[n][0] = fmaf(fmaxf(hi4.y + h1.x, 0.f), wq.y, sp[n][0]);
                sp[n][0] = fmaf(fmaxf(hi4.z + h2.x, 0.f), wq.z, sp[n][0]);
                sp[n][0] = fmaf(fmaxf(hi4.w + h3.x, 0.f), wq.w, sp[n][0]);
                sp[n][1] = fmaf(fmaxf(hi4.x + h0.y, 0.f), wq.x, sp[n][1]);
                sp[n][1] = fmaf(fmaxf(hi4.y + h1.y, 0.f), wq.y, sp[n][1]);
                sp[n][1] = fmaf(fmaxf(hi4.z + h2.y, 0.f), wq.z, sp[n][1]);
                sp[n][1] = fmaf(fmaxf(hi4.w + h3.y, 0.f), wq.w, sp[n][1]);
                sp[n][2] = fmaf(fmaxf(hi4.x + h0.z, 0.f), wq.x, sp[n][2]);
                sp[n][2] = fmaf(fmaxf(hi4.y + h1.z, 0.f), wq.y, sp[n][2]);
                sp[n][2] = fmaf(fmaxf(hi4.z + h2.z, 0.f), wq.z, sp[n][2]);
                sp[n][2] = fmaf(fmaxf(hi4.w + h3.z, 0.f), wq.w, sp[n][2]);
                sp[n][3] = fmaf(fmaxf(hi4.x + h0.w, 0.f), wq.x, sp[n][3]);
                sp[n][3] = fmaf(fmaxf(hi4.y + h1.w, 0.f), wq.y, sp[n][3]);
                sp[n][3] = fmaf(fmaxf(hi4.z + h2.w, 0.f), wq.z, sp[n][3]);
                sp[n][3] = fmaf(fmaxf(hi4.w + h3.w, 0.f), wq.w, sp[n][3]);
            }
        }
#pragma unroll
        for (int n = 0; n < 4; n++)
            *(float4*)&sred[w][n][4 * lane] =
                make_float4(sp[n][0], sp[n][1], sp[n][2], sp[n][3]);
    }
    __syncthreads();

    // ---- combine + softmax; thread t = m ----
    float b2v = b2[0];
    float s[4];
#pragma unroll
    for (int i = 0; i < 4; i++) {
        s[i] = ((sred[0][i][t] + sred[1][i][t]) +
                (sred[2][i][t] + sred[3][i][t])) + b2v;
        if (t == n0 + i) s[i] = 0.f;   // reference leaves diagonal exactly 0
    }
#pragma unroll
    for (int i = 0; i < 4; i++) {
        float m = wred_max(s[i]);
        if (lane == 0) part[i][w] = m;
    }
    __syncthreads();
    float ev[4];
#pragma unroll
    for (int i = 0; i < 4; i++) {
        float mx = fmaxf(fmaxf(part[i][0], part[i][1]),
                         fmaxf(part[i][2], part[i][3]));
        ev[i] = __expf(s[i] - mx);
        float sm = wred_sum(ev[i]);
        if (lane == 0) part[4 + i][w] = sm;
    }
    __syncthreads();
#pragma unroll
    for (int i = 0; i < 4; i++) {
        float tot = (part[4 + i][0] + part[4 + i][1]) +
                    (part[4 + i][2] + part[4 + i][3]);
        wt_s[i][t] = ev[i] / tot;
    }
    __syncthreads();

    // ---- phase 2: ctx. wave w: m in [64w,64w+64); lane: d=4*lane..+3 ----
    {
        const float* xpp = x + (size_t)b * 65536 + (size_t)(w * 64) * 256 + 4 * lane;
        float cp[4][4];
#pragma unroll
        for (int n = 0; n < 4; n++)
#pragma unroll
            for (int j = 0; j < 4; j++) cp[n][j] = 0.f;

#pragma unroll 4
        for (int mc = 0; mc < 64; mc += 4) {
            float4 x0 = *(const float4*)(xpp + (size_t)(mc + 0) * 256);
            float4 x1 = *(const float4*)(xpp + (size_t)(mc + 1) * 256);
            float4 x2 = *(const float4*)(xpp + (size_t)(mc + 2) * 256);
            float4 x3 = *(const float4*)(xpp + (size_t)(mc + 3) * 256);
#pragma unroll
            for (int n = 0; n < 4; n++) {
                float4 wt4 = *(const float4*)&wt_s[n][w * 64 + mc];
                cp[n][0] = fmaf(wt4.x, x0.x, cp[n][0]);
                cp[n][0] = fmaf(wt4.y, x1.x, cp[n][0]);
                cp[n][0] = fmaf(wt4.z, x2.x, cp[n][0]);
                cp[n][0] = fmaf(wt4.w, x3.x, cp[n][0]);
                cp[n][1] = fmaf(wt4.x, x0.y, cp[n][1]);
                cp[n][1] = fmaf(wt4.y, x1.y, cp[n][1]);
                cp[n][1] = fmaf(wt4.z, x2.y, cp[n][1]);
                cp[n][1] = fmaf(wt4.w, x3.y, cp[n][1]);
                cp[n][2] = fmaf(wt4.x, x0.z, cp[n][2]);
                cp[n][2] = fmaf(wt4.y, x1.z, cp[n][2]);
                cp[n][2] = fmaf(wt4.z, x2.z, cp[n][2]);
                cp[n][2] = fmaf(wt4.w, x3.z, cp[n][2]);
                cp[n][3] = fmaf(wt4.x, x0.w, cp[n][3]);
                cp[n][3] = fmaf(wt4.y, x1.w, cp[n][3]);
                cp[n][3] = fmaf(wt4.z, x2.w, cp[n][3]);
                cp[n][3] = fmaf(wt4.w, x3.w, cp[n][3]);
            }
        }
#pragma unroll
        for (int n = 0; n < 4; n++)
            *(float4*)&sred[w][n][4 * lane] =
                make_float4(cp[n][0], cp[n][1], cp[n][2], cp[n][3]);
    }
    __syncthreads();
#pragma unroll
    for (int i = 0; i < 4; i++)
        ctx_s[i][t] = (sred[0][i][t] + sred[1][i][t]) +
                      (sred[2][i][t] + sred[3][i][t]);
    __syncthreads();

    // ---- phase 3: proj. wave w: d in [64w,64w+64); lane: e=4*lane..+3 ----
    {
        const float* wpp = Wp + (size_t)(w * 64) * 256 + 4 * lane;
        float pq[4][4];
#pragma unroll
        for (int n = 0; n < 4; n++)
#pragma unroll
            for (int j = 0; j < 4; j++) pq[n][j] = 0.f;

#pragma unroll 4
        for (int dc = 0; dc < 64; dc += 4) {
            float4 q0 = *(const float4*)(wpp + (size_t)(dc + 0) * 256);
            float4 q1 = *(const float4*)(wpp + (size_t)(dc + 1) * 256);
            float4 q2 = *(const float4*)(wpp + (size_t)(dc + 2) * 256);
            float4 q3 = *(const float4*)(wpp + (size_t)(dc + 3) * 256);
#pragma unroll
            for (int n = 0; n < 4; n++) {
                float4 c4 = *(const float4*)&ctx_s[n][w * 64 + dc];
                pq[n][0] = fmaf(c4.x, q0.x, pq[n][0]);
                pq[n][0] = fmaf(c4.y, q1.x, pq[n][0]);
                pq[n][0] = fmaf(c4.z, q2.x, pq[n][0]);
                pq[n][0] = fmaf(c4.w, q3.x, pq[n][0]);
                pq[n][1] = fmaf(c4.x, q0.y, pq[n][1]);
                pq[n][1] = fmaf(c4.y, q1.y, pq[n][1]);
                pq[n][1] = fmaf(c4.z, q2.y, pq[n][1]);
                pq[n][1] = fmaf(c4.w, q3.y, pq[n][1]);
                pq[n][2] = fmaf(c4.x, q0.z, pq[n][2]);
                pq[n][2] = fmaf(c4.y, q1.z, pq[n][2]);
                pq[n][2] = fmaf(c4.z, q2.z, pq[n][2]);
                pq[n][2] = fmaf(c4.w, q3.z, pq[n][2]);
                pq[n][3] = fmaf(c4.x, q0.w, pq[n][3]);
                pq[n][3] = fmaf(c4.y, q1.w, pq[n][3]);
                pq[n][3] = fmaf(c4.z, q2.w, pq[n][3]);
                pq[n][3] = fmaf(c4.w, q3.w, pq[n][3]);
            }
        }
#pragma unroll
        for (int n = 0; n < 4; n++)
            *(float4*)&sred[w][n][4 * lane] =
                make_float4(pq[n][0], pq[n][1], pq[n][2], pq[n][3]);
    }
    __syncthreads();

    // ---- combine + LayerNorm + residual; thread t = e ----
    float bpv = bp[t];
    float p[4];
#pragma unroll
    for (int i = 0; i < 4; i++)
        p[i] = ((sred[0][i][t] + sred[1][i][t]) +
                (sred[2][i][t] + sred[3][i][t])) + bpv;

#pragma unroll
    for (int i = 0; i < 4; i++) {
        float su = wred_sum(p[i]);
        float sq = wred_sum(p[i] * p[i]);
        if (lane == 0) { part[i][w] = su; part[4 + i][w] = sq; }
    }
    __syncthreads();
    float gv = gma[t], bv = bta[t];
#pragma unroll
    for (int i = 0; i < 4; i++) {
        float su = (part[i][0] + part[i][1]) + (part[i][2] + part[i][3]);
        float sq = (part[4 + i][0] + part[4 + i][1]) +
                   (part[4 + i][2] + part[4 + i][3]);
        float mu = su * (1.f / 256.f);
        float var = sq * (1.f / 256.f) - mu * mu;
        float ln = (p[i] - mu) * rsqrtf(var + LN_EPS) * gv + bv;
        out[(size_t)(bn0 + i) * 256 + t] = x[(size_t)(bn0 + i) * 256 + t] + ln;
    }
}

extern "C" void kernel_launch(void* const* d_in, const int* in_sizes, int n_in,
                              void* d_out, int out_size, void* d_ws, size_t ws_size,
                              hipStream_t stream) {
    const float* x   = (const float*)d_in[0];
    const float* W1  = (const float*)d_in[1];
    const float* b1  = (const float*)d_in[2];
    const float* W2  = (const float*)d_in[3];
    const float* b2  = (const float*)d_in[4];
    const float* Wp  = (const float*)d_in[5];
    const float* bp  = (const float*)d_in[6];
    const float* gma = (const float*)d_in[7];
    const float* bta = (const float*)d_in[8];
    float* out = (float*)d_out;

    float* hi_ws = (float*)d_ws;                  // [2048,256] f32, 2 MB
    float* hjT   = hi_ws + (size_t)2048 * 256;    // [8,256,256] f32, 2 MB

    k_gemm_hij<<<256, 256, 0, stream>>>(x, W1, b1, hi_ws, hjT);
    k_fused<<<512, 256, 0, stream>>>(x, hi_ws, hjT, W2, b2, Wp, bp,
                                     gma, bta, out);
}

// Round 7
// 116.840 us; speedup vs baseline: 1.0990x; 1.0990x over previous
//
#include <hip/hip_runtime.h>

#define LN_EPS 1e-5f

__device__ __forceinline__ float wred_max(float v) {
#pragma unroll
    for (int off = 32; off; off >>= 1) v = fmaxf(v, __shfl_xor(v, off, 64));
    return v;
}
__device__ __forceinline__ float wred_sum(float v) {
#pragma unroll
    for (int off = 32; off; off >>= 1) v += __shfl_xor(v, off, 64);
    return v;
}

// Kernel 1: hi_ws[row][e] = x[row]·W1[:256][e] + b1[e]
//           hjT[b][e][m]  = x[b*256+m]·W1[256:][e]   (transposed store)
// 512 blocks × 256 thr, 4 rows/block. XCD swizzle: batch = blockIdx&7 so
// batch-b rows run on XCD b (matches k_fused's swizzle -> hi/hjT/x stay in
// XCD-local L2). Wave w owns output cols [128w,128w+128) (half = w>>1,
// uniform); lane owns 2 cols (float2). W1 read exactly once per block.
__global__ __launch_bounds__(256) void k_gemm_hij(
    const float* __restrict__ x,    // [2048,256]
    const float* __restrict__ W1,   // [512,256]
    const float* __restrict__ b1,   // [256]
    float* __restrict__ hi_ws,      // [2048,256]
    float* __restrict__ hjT)        // [8,256,256] (b, e, m)
{
    __shared__ __align__(16) float xs[4][256];
    const int t = threadIdx.x;
    const int lane = t & 63, w = t >> 6;
    const int b = blockIdx.x & 7;
    const int i = blockIdx.x >> 3;          // 0..63
    const int row0 = b * 256 + i * 4;

    ((float4*)xs)[t] = ((const float4*)(x + (size_t)row0 * 256))[t];
    __syncthreads();

    const int half = w >> 1;
    const int e0 = ((w & 1) << 7) + 2 * lane;   // 2-col slice within half
    const float* Wb = W1 + (size_t)half * 65536 + e0;

    float acc[4][2];
#pragma unroll
    for (int r = 0; r < 4; r++) { acc[r][0] = 0.f; acc[r][1] = 0.f; }

#pragma unroll 2
    for (int k = 0; k < 256; k += 8) {
        float2 q[8];
#pragma unroll
        for (int j = 0; j < 8; j++)
            q[j] = *(const float2*)(Wb + (size_t)(k + j) * 256);
#pragma unroll
        for (int r = 0; r < 4; r++) {
            float4 xa = *(const float4*)&xs[r][k];
            float4 xb = *(const float4*)&xs[r][k + 4];
            acc[r][0] = fmaf(xa.x, q[0].x, acc[r][0]);
            acc[r][1] = fmaf(xa.x, q[0].y, acc[r][1]);
            acc[r][0] = fmaf(xa.y, q[1].x, acc[r][0]);
            acc[r][1] = fmaf(xa.y, q[1].y, acc[r][1]);
            acc[r][0] = fmaf(xa.z, q[2].x, acc[r][0]);
            acc[r][1] = fmaf(xa.z, q[2].y, acc[r][1]);
            acc[r][0] = fmaf(xa.w, q[3].x, acc[r][0]);
            acc[r][1] = fmaf(xa.w, q[3].y, acc[r][1]);
            acc[r][0] = fmaf(xb.x, q[4].x, acc[r][0]);
            acc[r][1] = fmaf(xb.x, q[4].y, acc[r][1]);
            acc[r][0] = fmaf(xb.y, q[5].x, acc[r][0]);
            acc[r][1] = fmaf(xb.y, q[5].y, acc[r][1]);
            acc[r][0] = fmaf(xb.z, q[6].x, acc[r][0]);
            acc[r][1] = fmaf(xb.z, q[6].y, acc[r][1]);
            acc[r][0] = fmaf(xb.w, q[7].x, acc[r][0]);
            acc[r][1] = fmaf(xb.w, q[7].y, acc[r][1]);
        }
    }

    if (half == 0) {
        float2 bb = *(const float2*)(b1 + e0);
#pragma unroll
        for (int r = 0; r < 4; r++)
            *(float2*)&hi_ws[(size_t)(row0 + r) * 256 + e0] =
                make_float2(acc[r][0] + bb.x, acc[r][1] + bb.y);
    } else {
        const int m0 = i * 4;
        *(float4*)&hjT[(size_t)b * 65536 + (size_t)e0 * 256 + m0] =
            make_float4(acc[0][0], acc[1][0], acc[2][0], acc[3][0]);
        *(float4*)&hjT[(size_t)b * 65536 + (size_t)(e0 + 1) * 256 + m0] =
            make_float4(acc[0][1], acc[1][1], acc[2][1], acc[3][1]);
    }
}

// Kernel 2: 4 n's per block, 512 blocks × 4 waves.
// XCD swizzle: b = blockIdx & 7 -> all blocks of batch b on XCD b. Per-XCD L2
// working set ~1 MB (hjT[b]+x[b]+hi[b]+Wp) << 4 MB, and k_gemm wrote batch b's
// intermediates through the same XCD's L2.
__global__ __launch_bounds__(256) void k_fused(
    const float* __restrict__ x,      // [8,256,256]
    const float* __restrict__ hi_ws,  // [2048,256] (b1 folded)
    const float* __restrict__ hjT,    // [8,256,256] (b, d, m)
    const float* __restrict__ W2, const float* __restrict__ b2,
    const float* __restrict__ Wp, const float* __restrict__ bp,
    const float* __restrict__ gma, const float* __restrict__ bta,
    float* __restrict__ out)
{
    const int t = threadIdx.x;
    const int lane = t & 63, w = t >> 6;
    const int b = blockIdx.x & 7;          // XCD-local batch
    const int n0 = (blockIdx.x >> 3) * 4;  // n-tile within batch
    const int bn0 = b * 256 + n0;

    __shared__ __align__(16) float hi_s[4][256];
    __shared__ __align__(16) float w2_s[256];
    __shared__ __align__(16) float wt_s[4][256];
    __shared__ __align__(16) float ctx_s[4][256];
    __shared__ __align__(16) float sred[4][4][256];   // [wave][n][out]
    __shared__ float part[8][4];

#pragma unroll
    for (int i = 0; i < 4; i++) hi_s[i][t] = hi_ws[(size_t)(bn0 + i) * 256 + t];
    w2_s[t] = W2[t];
    __syncthreads();

    // ---- phase 1: partial scores. wave w: d in [64w,64w+64); lane: m=4*lane..+3
    {
        const float* hjp = hjT + (size_t)b * 65536 + (size_t)(w * 64) * 256 + 4 * lane;
        float sp[4][4];
#pragma unroll
        for (int n = 0; n < 4; n++)
#pragma unroll
            for (int j = 0; j < 4; j++) sp[n][j] = 0.f;

#pragma unroll 4
        for (int dc = 0; dc < 64; dc += 4) {
            float4 h0 = *(const float4*)(hjp + (size_t)(dc + 0) * 256);
            float4 h1 = *(const float4*)(hjp + (size_t)(dc + 1) * 256);
            float4 h2 = *(const float4*)(hjp + (size_t)(dc + 2) * 256);
            float4 h3 = *(const float4*)(hjp + (size_t)(dc + 3) * 256);
            float4 wq = *(const float4*)&w2_s[w * 64 + dc];
#pragma unroll
            for (int n = 0; n < 4; n++) {
                float4 hi4 = *(const float4*)&hi_s[n][w * 64 + dc];
                sp[n][0] = fmaf(fmaxf(hi4.x + h0.x, 0.f), wq.x, sp[n][0]);
                sp[n][0] = fmaf(fmaxf(hi4.y + h1.x, 0.f), wq.y, sp[n][0]);
                sp[n][0] = fmaf(fmaxf(hi4.z + h2.x, 0.f), wq.z, sp[n][0]);
                sp[n][0] = fmaf(fmaxf(hi4.w + h3.x, 0.f), wq.w, sp[n][0]);
                sp[n][1] = fmaf(fmaxf(hi4.x + h0.y, 0.f), wq.x, sp[n][1]);
                sp[n][1] = fmaf(fmaxf(hi4.y + h1.y, 0.f), wq.y, sp[n][1]);
                sp[n][1] = fmaf(fmaxf(hi4.z + h2.y, 0.f), wq.z, sp[n][1]);
                sp[n][1] = fmaf(fmaxf(hi4.w + h3.y, 0.f), wq.w, sp[n][1]);
                sp[n][2] = fmaf(fmaxf(hi4.x + h0.z, 0.f), wq.x, sp[n][2]);
                sp[n][2] = fmaf(fmaxf(hi4.y + h1.z, 0.f), wq.y, sp[n][2]);
                sp[n][2] = fmaf(fmaxf(hi4.z + h2.z, 0.f), wq.z, sp[n][2]);
                sp[n][2] = fmaf(fmaxf(hi4.w + h3.z, 0.f), wq.w, sp[n][2]);
                sp[n][3] = fmaf(fmaxf(hi4.x + h0.w, 0.f), wq.x, sp[n][3]);
                sp[n][3] = fmaf(fmaxf(hi4.y + h1.w, 0.f), wq.y, sp[n][3]);
                sp[n][3] = fmaf(fmaxf(hi4.z + h2.w, 0.f), wq.z, sp[n][3]);
                sp[n][3] = fmaf(fmaxf(hi4.w + h3.w, 0.f), wq.w, sp[n][3]);
            }
        }
#pragma unroll
        for (int n = 0; n < 4; n++)
            *(float4*)&sred[w][n][4 * lane] =
                make_float4(sp[n][0], sp[n][1], sp[n][2], sp[n][3]);
    }
    __syncthreads();

    // ---- combine + softmax; thread t = m ----
    float b2v = b2[0];
    float s[4];
#pragma unroll
    for (int i = 0; i < 4; i++) {
        s[i] = ((sred[0][i][t] + sred[1][i][t]) +
                (sred[2][i][t] + sred[3][i][t])) + b2v;
        if (t == n0 + i) s[i] = 0.f;   // reference leaves diagonal exactly 0
    }
#pragma unroll
    for (int i = 0; i < 4; i++) {
        float m = wred_max(s[i]);
        if (lane == 0) part[i][w] = m;
    }
    __syncthreads();
    float ev[4];
#pragma unroll
    for (int i = 0; i < 4; i++) {
        float mx = fmaxf(fmaxf(part[i][0], part[i][1]),
                         fmaxf(part[i][2], part[i][3]));
        ev[i] = __expf(s[i] - mx);
        float sm = wred_sum(ev[i]);
        if (lane == 0) part[4 + i][w] = sm;
    }
    __syncthreads();
#pragma unroll
    for (int i = 0; i < 4; i++) {
        float tot = (part[4 + i][0] + part[4 + i][1]) +
                    (part[4 + i][2] + part[4 + i][3]);
        wt_s[i][t] = ev[i] / tot;
    }
    __syncthreads();

    // ---- phase 2: ctx. wave w: m in [64w,64w+64); lane: d=4*lane..+3 ----
    {
        const float* xpp = x + (size_t)b * 65536 + (size_t)(w * 64) * 256 + 4 * lane;
        float cp[4][4];
#pragma unroll
        for (int n = 0; n < 4; n++)
#pragma unroll
            for (int j = 0; j < 4; j++) cp[n][j] = 0.f;

#pragma unroll 4
        for (int mc = 0; mc < 64; mc += 4) {
            float4 x0 = *(const float4*)(xpp + (size_t)(mc + 0) * 256);
            float4 x1 = *(const float4*)(xpp + (size_t)(mc + 1) * 256);
            float4 x2 = *(const float4*)(xpp + (size_t)(mc + 2) * 256);
            float4 x3 = *(const float4*)(xpp + (size_t)(mc + 3) * 256);
#pragma unroll
            for (int n = 0; n < 4; n++) {
                float4 wt4 = *(const float4*)&wt_s[n][w * 64 + mc];
                cp[n][0] = fmaf(wt4.x, x0.x, cp[n][0]);
                cp[n][0] = fmaf(wt4.y, x1.x, cp[n][0]);
                cp[n][0] = fmaf(wt4.z, x2.x, cp[n][0]);
                cp[n][0] = fmaf(wt4.w, x3.x, cp[n][0]);
                cp[n][1] = fmaf(wt4.x, x0.y, cp[n][1]);
                cp[n][1] = fmaf(wt4.y, x1.y, cp[n][1]);
                cp[n][1] = fmaf(wt4.z, x2.y, cp[n][1]);
                cp[n][1] = fmaf(wt4.w, x3.y, cp[n][1]);
                cp[n][2] = fmaf(wt4.x, x0.z, cp[n][2]);
                cp[n][2] = fmaf(wt4.y, x1.z, cp[n][2]);
                cp[n][2] = fmaf(wt4.z, x2.z, cp[n][2]);
                cp[n][2] = fmaf(wt4.w, x3.z, cp[n][2]);
                cp[n][3] = fmaf(wt4.x, x0.w, cp[n][3]);
                cp[n][3] = fmaf(wt4.y, x1.w, cp[n][3]);
                cp[n][3] = fmaf(wt4.z, x2.w, cp[n][3]);
                cp[n][3] = fmaf(wt4.w, x3.w, cp[n][3]);
            }
        }
#pragma unroll
        for (int n = 0; n < 4; n++)
            *(float4*)&sred[w][n][4 * lane] =
                make_float4(cp[n][0], cp[n][1], cp[n][2], cp[n][3]);
    }
    __syncthreads();
#pragma unroll
    for (int i = 0; i < 4; i++)
        ctx_s[i][t] = (sred[0][i][t] + sred[1][i][t]) +
                      (sred[2][i][t] + sred[3][i][t]);
    __syncthreads();

    // ---- phase 3: proj. wave w: d in [64w,64w+64); lane: e=4*lane..+3 ----
    {
        const float* wpp = Wp + (size_t)(w * 64) * 256 + 4 * lane;
        float pq[4][4];
#pragma unroll
        for (int n = 0; n < 4; n++)
#pragma unroll
            for (int j = 0; j < 4; j++) pq[n][j] = 0.f;

#pragma unroll 4
        for (int dc = 0; dc < 64; dc += 4) {
            float4 q0 = *(const float4*)(wpp + (size_t)(dc + 0) * 256);
            float4 q1 = *(const float4*)(wpp + (size_t)(dc + 1) * 256);
            float4 q2 = *(const float4*)(wpp + (size_t)(dc + 2) * 256);
            float4 q3 = *(const float4*)(wpp + (size_t)(dc + 3) * 256);
#pragma unroll
            for (int n = 0; n < 4; n++) {
                float4 c4 = *(const float4*)&ctx_s[n][w * 64 + dc];
                pq[n][0] = fmaf(c4.x, q0.x, pq[n][0]);
                pq[n][0] = fmaf(c4.y, q1.x, pq[n][0]);
                pq[n][0] = fmaf(c4.z, q2.x, pq[n][0]);
                pq[n][0] = fmaf(c4.w, q3.x, pq[n][0]);
                pq[n][1] = fmaf(c4.x, q0.y, pq[n][1]);
                pq[n][1] = fmaf(c4.y, q1.y, pq[n][1]);
                pq[n][1] = fmaf(c4.z, q2.y, pq[n][1]);
                pq[n][1] = fmaf(c4.w, q3.y, pq[n][1]);
                pq[n][2] = fmaf(c4.x, q0.z, pq[n][2]);
                pq[n][2] = fmaf(c4.y, q1.z, pq[n][2]);
                pq[n][2] = fmaf(c4.z, q2.z, pq[n][2]);
                pq[n][2] = fmaf(c4.w, q3.z, pq[n][2]);
                pq[n][3] = fmaf(c4.x, q0.w, pq[n][3]);
                pq[n][3] = fmaf(c4.y, q1.w, pq[n][3]);
                pq[n][3] = fmaf(c4.z, q2.w, pq[n][3]);
                pq[n][3] = fmaf(c4.w, q3.w, pq[n][3]);
            }
        }
#pragma unroll
        for (int n = 0; n < 4; n++)
            *(float4*)&sred[w][n][4 * lane] =
                make_float4(pq[n][0], pq[n][1], pq[n][2], pq[n][3]);
    }
    __syncthreads();

    // ---- combine + LayerNorm + residual; thread t = e ----
    float bpv = bp[t];
    float p[4];
#pragma unroll
    for (int i = 0; i < 4; i++)
        p[i] = ((sred[0][i][t] + sred[1][i][t]) +
                (sred[2][i][t] + sred[3][i][t])) + bpv;

#pragma unroll
    for (int i = 0; i < 4; i++) {
        float su = wred_sum(p[i]);
        float sq = wred_sum(p[i] * p[i]);
        if (lane == 0) { part[i][w] = su; part[4 + i][w] = sq; }
    }
    __syncthreads();
    float gv = gma[t], bv = bta[t];
#pragma unroll
    for (int i = 0; i < 4; i++) {
        float su = (part[i][0] + part[i][1]) + (part[i][2] + part[i][3]);
        float sq = (part[4 + i][0] + part[4 + i][1]) +
                   (part[4 + i][2] + part[4 + i][3]);
        float mu = su * (1.f / 256.f);
        float var = sq * (1.f / 256.f) - mu * mu;
        float ln = (p[i] - mu) * rsqrtf(var + LN_EPS) * gv + bv;
        out[(size_t)(bn0 + i) * 256 + t] = x[(size_t)(bn0 + i) * 256 + t] + ln;
    }
}

extern "C" void kernel_launch(void* const* d_in, const int* in_sizes, int n_in,
                              void* d_out, int out_size, void* d_ws, size_t ws_size,
                              hipStream_t stream) {
    const float* x   = (const float*)d_in[0];
    const float* W1  = (const float*)d_in[1];
    const float* b1  = (const float*)d_in[2];
    const float* W2  = (const float*)d_in[3];
    const float* b2  = (const float*)d_in[4];
    const float* Wp  = (const float*)d_in[5];
    const float* bp  = (const float*)d_in[6];
    const float* gma = (const float*)d_in[7];
    const float* bta = (const float*)d_in[8];
    float* out = (float*)d_out;

    float* hi_ws = (float*)d_ws;                  // [2048,256] f32, 2 MB
    float* hjT   = hi_ws + (size_t)2048 * 256;    // [8,256,256] f32, 2 MB

    k_gemm_hij<<<512, 256, 0, stream>>>(x, W1, b1, hi_ws, hjT);
    k_fused<<<512, 256, 0, stream>>>(x, hi_ws, hjT, W2, b2, Wp, bp,
                                     gma, bta, out);
}

// Round 8
// 108.851 us; speedup vs baseline: 1.1797x; 1.0734x over previous
//
#include <hip/hip_runtime.h>

#define LN_EPS 1e-5f

__device__ __forceinline__ float wred_max(float v) {
#pragma unroll
    for (int off = 32; off; off >>= 1) v = fmaxf(v, __shfl_xor(v, off, 64));
    return v;
}
__device__ __forceinline__ float wred_sum(float v) {
#pragma unroll
    for (int off = 32; off; off >>= 1) v += __shfl_xor(v, off, 64);
    return v;
}

// ---------------- Kernel 1: software-pipelined dual GEMM ----------------
// hi_ws[row][e] = x[row]·W1[:256][e] + b1[e];  hjT[b][e][m] = x[row]·W1[256:][e]
// 512 blocks × 256 thr, 4 rows/block, XCD swizzle (batch = blockIdx&7).
// Wave w: half = w>>1, cols e0 = ((w&1)<<7)+2*lane. W1 read once per block.
// Register double-buffer: prefetch k-batch kb+1 while computing kb.

#define GL(Q, KB) { const float* _p = Wb + (size_t)((KB) * 8) * 256;            \
    _Pragma("unroll") for (int _j = 0; _j < 8; _j++)                            \
        Q[_j] = *(const float2*)(_p + (size_t)_j * 256); }

#define GC(Q, KB) { const int _k = (KB) * 8;                                    \
    _Pragma("unroll") for (int _r = 0; _r < 4; _r++) {                          \
        float4 _xa = *(const float4*)&xs[_r][_k];                               \
        float4 _xb = *(const float4*)&xs[_r][_k + 4];                           \
        acc[_r][0] = fmaf(_xa.x, Q[0].x, acc[_r][0]);                           \
        acc[_r][1] = fmaf(_xa.x, Q[0].y, acc[_r][1]);                           \
        acc[_r][0] = fmaf(_xa.y, Q[1].x, acc[_r][0]);                           \
        acc[_r][1] = fmaf(_xa.y, Q[1].y, acc[_r][1]);                           \
        acc[_r][0] = fmaf(_xa.z, Q[2].x, acc[_r][0]);                           \
        acc[_r][1] = fmaf(_xa.z, Q[2].y, acc[_r][1]);                           \
        acc[_r][0] = fmaf(_xa.w, Q[3].x, acc[_r][0]);                           \
        acc[_r][1] = fmaf(_xa.w, Q[3].y, acc[_r][1]);                           \
        acc[_r][0] = fmaf(_xb.x, Q[4].x, acc[_r][0]);                           \
        acc[_r][1] = fmaf(_xb.x, Q[4].y, acc[_r][1]);                           \
        acc[_r][0] = fmaf(_xb.y, Q[5].x, acc[_r][0]);                           \
        acc[_r][1] = fmaf(_xb.y, Q[5].y, acc[_r][1]);                           \
        acc[_r][0] = fmaf(_xb.z, Q[6].x, acc[_r][0]);                           \
        acc[_r][1] = fmaf(_xb.z, Q[6].y, acc[_r][1]);                           \
        acc[_r][0] = fmaf(_xb.w, Q[7].x, acc[_r][0]);                           \
        acc[_r][1] = fmaf(_xb.w, Q[7].y, acc[_r][1]); } }

__global__ __launch_bounds__(256) void k_gemm_hij(
    const float* __restrict__ x,    // [2048,256]
    const float* __restrict__ W1,   // [512,256]
    const float* __restrict__ b1,   // [256]
    float* __restrict__ hi_ws,      // [2048,256]
    float* __restrict__ hjT)        // [8,256,256] (b, e, m)
{
    __shared__ __align__(16) float xs[4][256];
    const int t = threadIdx.x;
    const int lane = t & 63, w = t >> 6;
    const int b = blockIdx.x & 7;
    const int i = blockIdx.x >> 3;          // 0..63
    const int row0 = b * 256 + i * 4;

    ((float4*)xs)[t] = ((const float4*)(x + (size_t)row0 * 256))[t];
    __syncthreads();

    const int half = w >> 1;
    const int e0 = ((w & 1) << 7) + 2 * lane;
    const float* Wb = W1 + (size_t)half * 65536 + e0;

    float acc[4][2];
#pragma unroll
    for (int r = 0; r < 4; r++) { acc[r][0] = 0.f; acc[r][1] = 0.f; }

    float2 qa[8], qb[8];
    GL(qa, 0);
    for (int kb = 0; kb + 2 < 32; kb += 2) {
        GL(qb, kb + 1);
        GC(qa, kb);
        GL(qa, kb + 2);
        GC(qb, kb + 1);
    }
    GL(qb, 31);
    GC(qa, 30);
    GC(qb, 31);

    if (half == 0) {
        float2 bb = *(const float2*)(b1 + e0);
#pragma unroll
        for (int r = 0; r < 4; r++)
            *(float2*)&hi_ws[(size_t)(row0 + r) * 256 + e0] =
                make_float2(acc[r][0] + bb.x, acc[r][1] + bb.y);
    } else {
        const int m0 = i * 4;
        *(float4*)&hjT[(size_t)b * 65536 + (size_t)e0 * 256 + m0] =
            make_float4(acc[0][0], acc[1][0], acc[2][0], acc[3][0]);
        *(float4*)&hjT[(size_t)b * 65536 + (size_t)(e0 + 1) * 256 + m0] =
            make_float4(acc[0][1], acc[1][1], acc[2][1], acc[3][1]);
    }
}

// ---------------- Kernel 2: fused, software-pipelined ----------------
// 4 n's per block, 512 blocks × 4 waves, XCD swizzle b = blockIdx&7.

// phase 1: groups of 4 d-rows (4 float4 loads), compute 192 VALU/group
#define P1L(H, G) { const float* _p = hjp + (size_t)((G) * 4) * 256;            \
    _Pragma("unroll") for (int _j = 0; _j < 4; _j++)                            \
        H[_j] = *(const float4*)(_p + (size_t)_j * 256); }

#define P1C(H, G) { const int _db = w * 64 + (G) * 4;                           \
    float4 _wq = *(const float4*)&w2_s[_db];                                    \
    _Pragma("unroll") for (int _n = 0; _n < 4; _n++) {                          \
        float4 _h4 = *(const float4*)&hi_s[_n][_db];                            \
        sp[_n][0] = fmaf(fmaxf(_h4.x + H[0].x, 0.f), _wq.x, sp[_n][0]);         \
        sp[_n][0] = fmaf(fmaxf(_h4.y + H[1].x, 0.f), _wq.y, sp[_n][0]);         \
        sp[_n][0] = fmaf(fmaxf(_h4.z + H[2].x, 0.f), _wq.z, sp[_n][0]);         \
        sp[_n][0] = fmaf(fmaxf(_h4.w + H[3].x, 0.f), _wq.w, sp[_n][0]);         \
        sp[_n][1] = fmaf(fmaxf(_h4.x + H[0].y, 0.f), _wq.x, sp[_n][1]);         \
        sp[_n][1] = fmaf(fmaxf(_h4.y + H[1].y, 0.f), _wq.y, sp[_n][1]);         \
        sp[_n][1] = fmaf(fmaxf(_h4.z + H[2].y, 0.f), _wq.z, sp[_n][1]);         \
        sp[_n][1] = fmaf(fmaxf(_h4.w + H[3].y, 0.f), _wq.w, sp[_n][1]);         \
        sp[_n][2] = fmaf(fmaxf(_h4.x + H[0].z, 0.f), _wq.x, sp[_n][2]);         \
        sp[_n][2] = fmaf(fmaxf(_h4.y + H[1].z, 0.f), _wq.y, sp[_n][2]);         \
        sp[_n][2] = fmaf(fmaxf(_h4.z + H[2].z, 0.f), _wq.z, sp[_n][2]);         \
        sp[_n][2] = fmaf(fmaxf(_h4.w + H[3].z, 0.f), _wq.w, sp[_n][2]);         \
        sp[_n][3] = fmaf(fmaxf(_h4.x + H[0].w, 0.f), _wq.x, sp[_n][3]);         \
        sp[_n][3] = fmaf(fmaxf(_h4.y + H[1].w, 0.f), _wq.y, sp[_n][3]);         \
        sp[_n][3] = fmaf(fmaxf(_h4.z + H[2].w, 0.f), _wq.z, sp[_n][3]);         \
        sp[_n][3] = fmaf(fmaxf(_h4.w + H[3].w, 0.f), _wq.w, sp[_n][3]); } }

// phases 2/3: groups of 8 rows (8 float4 loads), dot with LDS weight rows
#define DLOAD(X, PTR, G) { const float* _p = (PTR) + (size_t)((G) * 8) * 256;   \
    _Pragma("unroll") for (int _j = 0; _j < 8; _j++)                            \
        X[_j] = *(const float4*)(_p + (size_t)_j * 256); }

#define DCOMP(ACCV, WS, X, G) { const int _rb = w * 64 + (G) * 8;               \
    _Pragma("unroll") for (int _n = 0; _n < 4; _n++) {                          \
        float4 _wa = *(const float4*)&WS[_n][_rb];                              \
        float4 _wb = *(const float4*)&WS[_n][_rb + 4];                          \
        ACCV[_n][0] = fmaf(_wa.x, X[0].x, ACCV[_n][0]);                         \
        ACCV[_n][0] = fmaf(_wa.y, X[1].x, ACCV[_n][0]);                         \
        ACCV[_n][0] = fmaf(_wa.z, X[2].x, ACCV[_n][0]);                         \
        ACCV[_n][0] = fmaf(_wa.w, X[3].x, ACCV[_n][0]);                         \
        ACCV[_n][0] = fmaf(_wb.x, X[4].x, ACCV[_n][0]);                         \
        ACCV[_n][0] = fmaf(_wb.y, X[5].x, ACCV[_n][0]);                         \
        ACCV[_n][0] = fmaf(_wb.z, X[6].x, ACCV[_n][0]);                         \
        ACCV[_n][0] = fmaf(_wb.w, X[7].x, ACCV[_n][0]);                         \
        ACCV[_n][1] = fmaf(_wa.x, X[0].y, ACCV[_n][1]);                         \
        ACCV[_n][1] = fmaf(_wa.y, X[1].y, ACCV[_n][1]);                         \
        ACCV[_n][1] = fmaf(_wa.z, X[2].y, ACCV[_n][1]);                         \
        ACCV[_n][1] = fmaf(_wa.w, X[3].y, ACCV[_n][1]);                         \
        ACCV[_n][1] = fmaf(_wb.x, X[4].y, ACCV[_n][1]);                         \
        ACCV[_n][1] = fmaf(_wb.y, X[5].y, ACCV[_n][1]);                         \
        ACCV[_n][1] = fmaf(_wb.z, X[6].y, ACCV[_n][1]);                         \
        ACCV[_n][1] = fmaf(_wb.w, X[7].y, ACCV[_n][1]);                         \
        ACCV[_n][2] = fmaf(_wa.x, X[0].z, ACCV[_n][2]);                         \
        ACCV[_n][2] = fmaf(_wa.y, X[1].z, ACCV[_n][2]);                         \
        ACCV[_n][2] = fmaf(_wa.z, X[2].z, ACCV[_n][2]);                         \
        ACCV[_n][2] = fmaf(_wa.w, X[3].z, ACCV[_n][2]);                         \
        ACCV[_n][2] = fmaf(_wb.x, X[4].z, ACCV[_n][2]);                         \
        ACCV[_n][2] = fmaf(_wb.y, X[5].z, ACCV[_n][2]);                         \
        ACCV[_n][2] = fmaf(_wb.z, X[6].z, ACCV[_n][2]);                         \
        ACCV[_n][2] = fmaf(_wb.w, X[7].z, ACCV[_n][2]);                         \
        ACCV[_n][3] = fmaf(_wa.x, X[0].w, ACCV[_n][3]);                         \
        ACCV[_n][3] = fmaf(_wa.y, X[1].w, ACCV[_n][3]);                         \
        ACCV[_n][3] = fmaf(_wa.z, X[2].w, ACCV[_n][3]);                         \
        ACCV[_n][3] = fmaf(_wa.w, X[3].w, ACCV[_n][3]);                         \
        ACCV[_n][3] = fmaf(_wb.x, X[4].w, ACCV[_n][3]);                         \
        ACCV[_n][3] = fmaf(_wb.y, X[5].w, ACCV[_n][3]);                         \
        ACCV[_n][3] = fmaf(_wb.z, X[6].w, ACCV[_n][3]);                         \
        ACCV[_n][3] = fmaf(_wb.w, X[7].w, ACCV[_n][3]); } }

__global__ __launch_bounds__(256) void k_fused(
    const float* __restrict__ x,      // [8,256,256]
    const float* __restrict__ hi_ws,  // [2048,256] (b1 folded)
    const float* __restrict__ hjT,    // [8,256,256] (b, d, m)
    const float* __restrict__ W2, const float* __restrict__ b2,
    const float* __restrict__ Wp, const float* __restrict__ bp,
    const float* __restrict__ gma, const float* __restrict__ bta,
    float* __restrict__ out)
{
    const int t = threadIdx.x;
    const int lane = t & 63, w = t >> 6;
    const int b = blockIdx.x & 7;          // XCD-local batch
    const int n0 = (blockIdx.x >> 3) * 4;  // n-tile within batch
    const int bn0 = b * 256 + n0;

    __shared__ __align__(16) float hi_s[4][256];
    __shared__ __align__(16) float w2_s[256];
    __shared__ __align__(16) float wt_s[4][256];
    __shared__ __align__(16) float ctx_s[4][256];
    __shared__ __align__(16) float sred[4][4][256];   // [wave][n][out]
    __shared__ float part[8][4];

#pragma unroll
    for (int i = 0; i < 4; i++) hi_s[i][t] = hi_ws[(size_t)(bn0 + i) * 256 + t];
    w2_s[t] = W2[t];
    __syncthreads();

    // ---- phase 1: partial scores. wave w: d in [64w,64w+64); lane: m=4*lane..+3
    {
        const float* hjp = hjT + (size_t)b * 65536 + (size_t)(w * 64) * 256 + 4 * lane;
        float sp[4][4];
#pragma unroll
        for (int n = 0; n < 4; n++)
#pragma unroll
            for (int j = 0; j < 4; j++) sp[n][j] = 0.f;

        float4 ha[4], hb[4];
        P1L(ha, 0);
        for (int g = 0; g + 2 < 16; g += 2) {
            P1L(hb, g + 1);
            P1C(ha, g);
            P1L(ha, g + 2);
            P1C(hb, g + 1);
        }
        P1L(hb, 15);
        P1C(ha, 14);
        P1C(hb, 15);

#pragma unroll
        for (int n = 0; n < 4; n++)
            *(float4*)&sred[w][n][4 * lane] =
                make_float4(sp[n][0], sp[n][1], sp[n][2], sp[n][3]);
    }
    __syncthreads();

    // ---- combine + softmax; thread t = m ----
    float b2v = b2[0];
    float s[4];
#pragma unroll
    for (int i = 0; i < 4; i++) {
        s[i] = ((sred[0][i][t] + sred[1][i][t]) +
                (sred[2][i][t] + sred[3][i][t])) + b2v;
        if (t == n0 + i) s[i] = 0.f;   // reference leaves diagonal exactly 0
    }
#pragma unroll
    for (int i = 0; i < 4; i++) {
        float m = wred_max(s[i]);
        if (lane == 0) part[i][w] = m;
    }
    __syncthreads();
    float ev[4];
#pragma unroll
    for (int i = 0; i < 4; i++) {
        float mx = fmaxf(fmaxf(part[i][0], part[i][1]),
                         fmaxf(part[i][2], part[i][3]));
        ev[i] = __expf(s[i] - mx);
        float sm = wred_sum(ev[i]);
        if (lane == 0) part[4 + i][w] = sm;
    }
    __syncthreads();
#pragma unroll
    for (int i = 0; i < 4; i++) {
        float tot = (part[4 + i][0] + part[4 + i][1]) +
                    (part[4 + i][2] + part[4 + i][3]);
        wt_s[i][t] = ev[i] / tot;
    }
    __syncthreads();

    // ---- phase 2: ctx. wave w: m in [64w,64w+64); lane: d=4*lane..+3 ----
    {
        const float* xpp = x + (size_t)b * 65536 + (size_t)(w * 64) * 256 + 4 * lane;
        float cp[4][4];
#pragma unroll
        for (int n = 0; n < 4; n++)
#pragma unroll
            for (int j = 0; j < 4; j++) cp[n][j] = 0.f;

        float4 xa[8], xb[8];
        DLOAD(xa, xpp, 0);
        for (int g = 0; g + 2 < 8; g += 2) {
            DLOAD(xb, xpp, g + 1);
            DCOMP(cp, wt_s, xa, g);
            DLOAD(xa, xpp, g + 2);
            DCOMP(cp, wt_s, xb, g + 1);
        }
        DLOAD(xb, xpp, 7);
        DCOMP(cp, wt_s, xa, 6);
        DCOMP(cp, wt_s, xb, 7);

#pragma unroll
        for (int n = 0; n < 4; n++)
            *(float4*)&sred[w][n][4 * lane] =
                make_float4(cp[n][0], cp[n][1], cp[n][2], cp[n][3]);
    }
    __syncthreads();
#pragma unroll
    for (int i = 0; i < 4; i++)
        ctx_s[i][t] = (sred[0][i][t] + sred[1][i][t]) +
                      (sred[2][i][t] + sred[3][i][t]);
    __syncthreads();

    // ---- phase 3: proj. wave w: d in [64w,64w+64); lane: e=4*lane..+3 ----
    {
        const float* wpp = Wp + (size_t)(w * 64) * 256 + 4 * lane;
        float pq[4][4];
#pragma unroll
        for (int n = 0; n < 4; n++)
#pragma unroll
            for (int j = 0; j < 4; j++) pq[n][j] = 0.f;

        float4 qa4[8], qb4[8];
        DLOAD(qa4, wpp, 0);
        for (int g = 0; g + 2 < 8; g += 2) {
            DLOAD(qb4, wpp, g + 1);
            DCOMP(pq, ctx_s, qa4, g);
            DLOAD(qa4, wpp, g + 2);
            DCOMP(pq, ctx_s, qb4, g + 1);
        }
        DLOAD(qb4, wpp, 7);
        DCOMP(pq, ctx_s, qa4, 6);
        DCOMP(pq, ctx_s, qb4, 7);

#pragma unroll
        for (int n = 0; n < 4; n++)
            *(float4*)&sred[w][n][4 * lane] =
                make_float4(pq[n][0], pq[n][1], pq[n][2], pq[n][3]);
    }
    __syncthreads();

    // ---- combine + LayerNorm + residual; thread t = e ----
    float bpv = bp[t];
    float p[4];
#pragma unroll
    for (int i = 0; i < 4; i++)
        p[i] = ((sred[0][i][t] + sred[1][i][t]) +
                (sred[2][i][t] + sred[3][i][t])) + bpv;

#pragma unroll
    for (int i = 0; i < 4; i++) {
        float su = wred_sum(p[i]);
        float sq = wred_sum(p[i] * p[i]);
        if (lane == 0) { part[i][w] = su; part[4 + i][w] = sq; }
    }
    __syncthreads();
    float gv = gma[t], bv = bta[t];
#pragma unroll
    for (int i = 0; i < 4; i++) {
        float su = (part[i][0] + part[i][1]) + (part[i][2] + part[i][3]);
        float sq = (part[4 + i][0] + part[4 + i][1]) +
                   (part[4 + i][2] + part[4 + i][3]);
        float mu = su * (1.f / 256.f);
        float var = sq * (1.f / 256.f) - mu * mu;
        float ln = (p[i] - mu) * rsqrtf(var + LN_EPS) * gv + bv;
        out[(size_t)(bn0 + i) * 256 + t] = x[(size_t)(bn0 + i) * 256 + t] + ln;
    }
}

extern "C" void kernel_launch(void* const* d_in, const int* in_sizes, int n_in,
                              void* d_out, int out_size, void* d_ws, size_t ws_size,
                              hipStream_t stream) {
    const float* x   = (const float*)d_in[0];
    const float* W1  = (const float*)d_in[1];
    const float* b1  = (const float*)d_in[2];
    const float* W2  = (const float*)d_in[3];
    const float* b2  = (const float*)d_in[4];
    const float* Wp  = (const float*)d_in[5];
    const float* bp  = (const float*)d_in[6];
    const float* gma = (const float*)d_in[7];
    const float* bta = (const float*)d_in[8];
    float* out = (float*)d_out;

    float* hi_ws = (float*)d_ws;                  // [2048,256] f32, 2 MB
    float* hjT   = hi_ws + (size_t)2048 * 256;    // [8,256,256] f32, 2 MB

    k_gemm_hij<<<512, 256, 0, stream>>>(x, W1, b1, hi_ws, hjT);
    k_fused<<<512, 256, 0, stream>>>(x, hi_ws, hjT, W2, b2, Wp, bp,
                                     gma, bta, out);
}